// Round 5
// baseline (907.010 us; speedup 1.0000x reference)
//
#include <hip/hip_runtime.h>
#include <cstddef>
#include <cstdint>

// Problem dims (fixed by reference setup_inputs)
#define N_PATCH 100000
#define D_IN    1024
#define A_DIM   128
#define H_DIM   256
#define KTOP    16

// d_out layout (fp32 flat, reference return order)
#define OUT_LOGIT 0
#define OUT_EMB   1
#define OUT_FW    (1 + D_IN)             // 1025
#define OUT_TOPI  (OUT_FW + N_PATCH)     // 101025

// score-stage grid
#define NBLK   782                        // ceil(100000/128)
#define NCAND  (NBLK * KTOP)              // 12512

// workspace layout (float units)
#define WS_CANDV  0
#define WS_CANDI  12544
#define WS_HPART  25088                   // 16*256 floats
#define WS_WPK    29184                   // 16384 uint4 = 65536 floats, 16B-aligned

typedef __attribute__((ext_vector_type(8))) short bf8_t;   // 8 bf16 (4 VGPRs)
typedef __attribute__((ext_vector_type(4))) float f4_t;    // MFMA C/D frag

// ---------------- Stage 0: prepack Wa1 -> bf16 (RNE) + zero full_weights -----
// chunk t in [0, 16384): lane=t&63, nt=(t>>6)&7, ks=t>>9
// chunk holds 8 bf16: element j -> W[k = ks*32 + (lane>>4)*8 + j][n = nt*16 + (lane&15)]
__global__ __launch_bounds__(256) void k_prepack(
    const float* __restrict__ Wa1, uint4* __restrict__ wpk,
    float* __restrict__ out_fw)
{
    int t = blockIdx.x * 256 + threadIdx.x;     // grid 64 blocks -> 16384 chunks
    int lane = t & 63;
    int nt   = (t >> 6) & 7;
    int ks   = t >> 9;
    int n  = nt * 16 + (lane & 15);
    int k0 = ks * 32 + ((lane >> 4) * 8);
    union { ushort u[8]; uint4 v; } o;
    #pragma unroll
    for (int j = 0; j < 8; ++j) {
        uint b = __float_as_uint(Wa1[(size_t)(k0 + j) * A_DIM + n]);
        // round-to-nearest-even bf16 (bias-free, unlike truncation)
        o.u[j] = (ushort)((b + 0x7fffu + ((b >> 16) & 1u)) >> 16);
    }
    wpk[t] = o.v;
    // zero full_weights (d_out is poisoned each iteration)
    for (int i = t; i < N_PATCH; i += 64 * 256) out_fw[i] = 0.f;
}

// ---------------- Stage 1: scores + per-block top-16 (bf16 MFMA) -------------
// Block: 256 thr = 4 waves; wave covers 32 rows x 128 cols; block = 128 rows.
// Single-term bf16 (RNE both sides): selection-safe; selected rows get an
// exact fp32 rescore downstream. Per-block tile rotation spreads HBM channels.
// Epilogue: block-local top-16 via wave-0 shfl argmax -> candv/candi. No
// global scores buffer at all.
__device__ __forceinline__ void cvt8(const float4& a, const float4& b, bf8_t& out)
{
    union { uint u[4]; bf8_t v; } O;
    asm("v_cvt_pk_bf16_f32 %0, %1, %2" : "=v"(O.u[0]) : "v"(a.x), "v"(a.y));
    asm("v_cvt_pk_bf16_f32 %0, %1, %2" : "=v"(O.u[1]) : "v"(a.z), "v"(a.w));
    asm("v_cvt_pk_bf16_f32 %0, %1, %2" : "=v"(O.u[2]) : "v"(b.x), "v"(b.y));
    asm("v_cvt_pk_bf16_f32 %0, %1, %2" : "=v"(O.u[3]) : "v"(b.z), "v"(b.w));
    out = O.v;
}

#define MFMA_BF16 __builtin_amdgcn_mfma_f32_16x16x32_bf16

// LDS-visibility barrier that does NOT drain vmcnt: global prefetch loads
// stay in flight across step boundaries.
#define BAR_LDS() do {                                          \
    asm volatile("s_waitcnt lgkmcnt(0)" ::: "memory");          \
    __builtin_amdgcn_s_barrier();                               \
    asm volatile("" ::: "memory");                              \
} while (0)

// Load A half PAR of iteration IT into buffer set BUF (all literals).
#define LOADA(BUF, IT, PAR) do {                                               \
    const int kg = (((t0 + (IT)) & 15) * 2 + (PAR)) * 32;                      \
    A##BUF[0] = *(const float4*)(pa0 + kg);                                    \
    A##BUF[1] = *(const float4*)(pa0 + kg + 4);                                \
    A##BUF[2] = *(const float4*)(pa1 + kg);                                    \
    A##BUF[3] = *(const float4*)(pa1 + kg + 4);                                \
} while (0)

// One k-step (= half an LDS tile). IT iter index, PAR half, BUF A-buffer set,
// BUFP LDS buffer parity — ALL compile-time literals.
#define SCORE_STEP(IT, PAR, BUF, BUFP) do {                                    \
    bf8_t ah0, ah1;                                                            \
    cvt8(A##BUF[0], A##BUF[1], ah0);                                           \
    cvt8(A##BUF[2], A##BUF[3], ah1);                                           \
    if ((PAR) == 0) {                                                          \
        _Pragma("unroll")                                                      \
        for (int i = 0; i < 4; ++i) sB[(BUFP) ^ 1][tid + i * 256] = bpre[i];   \
        const int vtp = (t0 + (IT) + 2) & 15;                                  \
        _Pragma("unroll")                                                      \
        for (int i = 0; i < 4; ++i) bpre[i] = wpk[vtp * 1024 + tid + i * 256]; \
    }                                                                          \
    LOADA(BUF, (IT) + 2, PAR);                                                 \
    const bf8_t* sBf = (const bf8_t*)sB[BUFP] + (PAR) * 512;                   \
    _Pragma("unroll")                                                          \
    for (int nt = 0; nt < 8; nt += 2) {                                        \
        bf8_t b0 = sBf[nt * 64 + ln];                                          \
        bf8_t b1 = sBf[(nt + 1) * 64 + ln];                                    \
        acc[0][nt]     = MFMA_BF16(ah0, b0, acc[0][nt],     0, 0, 0);          \
        acc[1][nt]     = MFMA_BF16(ah1, b0, acc[1][nt],     0, 0, 0);          \
        acc[0][nt + 1] = MFMA_BF16(ah0, b1, acc[0][nt + 1], 0, 0, 0);          \
        acc[1][nt + 1] = MFMA_BF16(ah1, b1, acc[1][nt + 1], 0, 0, 0);          \
    }                                                                          \
    if (PAR) BAR_LDS();                                                        \
} while (0)

__global__ __launch_bounds__(256) void k_scores(
    const float* __restrict__ x, const uint4* __restrict__ wpk,
    const float* __restrict__ ba1, const float* __restrict__ Wa2,
    const float* __restrict__ ba2, float* __restrict__ candv,
    int* __restrict__ candi)
{
    __shared__ uint4 sB[2][1024];   // 32 KB double buffer; 1 tile = 2 k-steps

    const int tid = threadIdx.x;
    const int ln  = tid & 63;
    const int q   = ln >> 4;      // k-quad
    const int c   = ln & 15;      // col selector (B) / row selector (A)
    const int wv  = tid >> 6;
    const int row0 = blockIdx.x * 128 + wv * 32;
    const int t0   = blockIdx.x & 15;   // per-block tile rotation (16 tiles)

    // A-stream pointers (fragment layout: row = c, k = q*8 + j)
    const int r0 = min(row0 + c,      N_PATCH - 1);
    const int r1 = min(row0 + 16 + c, N_PATCH - 1);
    const float* pa0 = x + (size_t)r0 * D_IN + q * 8;
    const float* pa1 = x + (size_t)r1 * D_IN + q * 8;

    f4_t acc[2][8];
    #pragma unroll
    for (int rt = 0; rt < 2; ++rt)
        #pragma unroll
        for (int nt = 0; nt < 8; ++nt)
            acc[rt][nt] = (f4_t){0.f, 0.f, 0.f, 0.f};

    // ---- prologue: stage tile t0 into LDS, prefetch tile t0+1, A iters 0+1 --
    uint4 bpre[4];
    {
        uint4 b0[4];
        #pragma unroll
        for (int i = 0; i < 4; ++i) b0[i] = wpk[t0 * 1024 + tid + i * 256];
        #pragma unroll
        for (int i = 0; i < 4; ++i) sB[0][tid + i * 256] = b0[i];
    }
    {
        const int t1 = (t0 + 1) & 15;
        #pragma unroll
        for (int i = 0; i < 4; ++i) bpre[i] = wpk[t1 * 1024 + tid + i * 256];
    }

    float4 AE0[4], AE1[4], AO0[4], AO1[4];   // even/odd iter x half, static
    LOADA(E0, 0, 0);
    LOADA(E1, 0, 1);
    LOADA(O0, 1, 0);
    LOADA(O1, 1, 1);

    BAR_LDS();

    for (int it = 0; it < 16; it += 2) {
        SCORE_STEP(it,     0, E0, 0);
        SCORE_STEP(it,     1, E1, 0);
        SCORE_STEP(it + 1, 0, O0, 1);
        SCORE_STEP(it + 1, 1, O1, 1);
    }

    // epilogue: +ba1, tanh, dot Wa2, reduce over the 16 lanes sharing rows;
    // then block-local top-16 into candv/candi (no global scores buffer).
    float b1v[8], w2v[8];
    #pragma unroll
    for (int nt = 0; nt < 8; ++nt) {
        b1v[nt] = ba1[nt * 16 + c];
        w2v[nt] = Wa2[nt * 16 + c];
    }
    const float b2 = ba2[0];

    float* sS = (float*)(void*)sB;   // reuse LDS: 128 row-scores
    #pragma unroll
    for (int rt = 0; rt < 2; ++rt)
        #pragma unroll
        for (int reg = 0; reg < 4; ++reg) {
            float p = 0.f;
            #pragma unroll
            for (int nt = 0; nt < 8; ++nt)
                p += tanhf(acc[rt][nt][reg] + b1v[nt]) * w2v[nt];
            #pragma unroll
            for (int off = 1; off < 16; off <<= 1)
                p += __shfl_xor(p, off, 64);
            if (c == 0) {
                int lrow = rt * 16 + q * 4 + reg;          // C/D: row = quad*4+reg
                int row  = row0 + lrow;
                sS[wv * 32 + lrow] = (row < N_PATCH) ? (p + b2) : -1e30f;
            }
        }
    __syncthreads();

    if (wv == 0) {
        float v0 = sS[ln], v1 = sS[ln + 64];
        int   i0 = ln,     i1 = ln + 64;
        for (int r = 0; r < KTOP; ++r) {
            bool f = (v0 > v1) || (v0 == v1 && i0 < i1);
            float mv = f ? v0 : v1;
            int   mi = f ? i0 : i1;
            #pragma unroll
            for (int off = 1; off < 64; off <<= 1) {
                float ov = __shfl_xor(mv, off, 64);
                int   oi = __shfl_xor(mi, off, 64);
                if (ov > mv || (ov == mv && oi < mi)) { mv = ov; mi = oi; }
            }
            if (ln == 0) {
                candv[blockIdx.x * KTOP + r] = mv;
                candi[blockIdx.x * KTOP + r] = blockIdx.x * 128 + mi;
            }
            if (mi == i0) v0 = -1e30f;
            if (mi == i1) v1 = -1e30f;
        }
    }
}

// ---------------- Stage 2: fused tail (16 blocks) ----------------------------
// Each block REDUNDANTLY: merges 12512 candidates -> top-16 set; exact fp32
// rescore of the 16 rows (full Wa1 stream from L2); sort+softmax.
// Then block b computes emb slice d in [b*64,(b+1)*64) + MLP1 partial.
// Block 0 scatters full_weights + top_idx.
__global__ __launch_bounds__(256) void k_tail(
    const float* __restrict__ candv, const int* __restrict__ candi,
    const float* __restrict__ x, const float* __restrict__ Wa1,
    const float* __restrict__ ba1, const float* __restrict__ Wa2,
    const float* __restrict__ ba2, const float* __restrict__ Wc1,
    float* __restrict__ out, float* __restrict__ hpart)
{
    __shared__ float svals[4096];
    __shared__ int   sidx[4096];
    __shared__ float rv[256];
    __shared__ int   rgx[256];
    __shared__ int   rsl[256];
    __shared__ int   sti[KTOP];
    __shared__ float exv[KTOP];
    __shared__ float attn[KTOP];
    __shared__ int   order[KTOP];
    __shared__ float semb[64];
    const int tid = threadIdx.x;

    // ---- phase 1a: per-thread top-16 over strided candidate scan -----------
    float tv[16]; int ti[16];
    #pragma unroll
    for (int j = 0; j < 16; ++j) { tv[j] = -1e30f; ti[j] = 0x7fffffff; }
    for (int i = tid; i < NCAND; i += 256) {
        float v = candv[i]; int gi = candi[i];
        if (v > tv[15] || (v == tv[15] && gi < ti[15])) {
            tv[15] = v; ti[15] = gi;
            #pragma unroll
            for (int j = 15; j > 0; --j) {
                if (tv[j] > tv[j-1] || (tv[j] == tv[j-1] && ti[j] < ti[j-1])) {
                    float fv = tv[j]; tv[j] = tv[j-1]; tv[j-1] = fv;
                    int   fi = ti[j]; ti[j] = ti[j-1]; ti[j-1] = fi;
                } else break;
            }
        }
    }
    #pragma unroll
    for (int j = 0; j < 16; ++j) { svals[tid * 16 + j] = tv[j]; sidx[tid * 16 + j] = ti[j]; }
    __syncthreads();

    // ---- phase 1b: 16-round destructive extract over the 4096 survivors ----
    for (int r = 0; r < KTOP; ++r) {
        float bv = -1e38f; int bg = 0x7fffffff; int bs = tid * 16;
        #pragma unroll
        for (int i = 0; i < 16; ++i) {
            int s = tid * 16 + i;
            float v = svals[s]; int g = sidx[s];
            if (v > bv || (v == bv && g < bg)) { bv = v; bg = g; bs = s; }
        }
        rv[tid] = bv; rgx[tid] = bg; rsl[tid] = bs;
        __syncthreads();
        for (int off = 128; off > 0; off >>= 1) {
            if (tid < off) {
                if (rv[tid + off] > rv[tid] ||
                    (rv[tid + off] == rv[tid] && rgx[tid + off] < rgx[tid])) {
                    rv[tid] = rv[tid + off]; rgx[tid] = rgx[tid + off]; rsl[tid] = rsl[tid + off];
                }
            }
            __syncthreads();
        }
        if (tid == 0) { sti[r] = rgx[0]; svals[rsl[0]] = -1e30f; }
        __syncthreads();
    }

    // ---- phase 2: EXACT fp32 rescore (16 threads/row x 8 cols each) --------
    // row = tid>>4 in [0,16), col chunk n0 = (tid&15)*8
    {
        const int row = tid >> 4, cc = tid & 15, n0 = cc * 8;
        const float* xr = x + (size_t)sti[row] * D_IN;
        float ac[8];
        #pragma unroll
        for (int j = 0; j < 8; ++j) ac[j] = 0.f;
        #pragma unroll 4
        for (int d = 0; d < D_IN; ++d) {
            const float xv = xr[d];
            const float4 w0 = *(const float4*)(Wa1 + (size_t)d * A_DIM + n0);
            const float4 w1 = *(const float4*)(Wa1 + (size_t)d * A_DIM + n0 + 4);
            ac[0] = fmaf(xv, w0.x, ac[0]); ac[1] = fmaf(xv, w0.y, ac[1]);
            ac[2] = fmaf(xv, w0.z, ac[2]); ac[3] = fmaf(xv, w0.w, ac[3]);
            ac[4] = fmaf(xv, w1.x, ac[4]); ac[5] = fmaf(xv, w1.y, ac[5]);
            ac[6] = fmaf(xv, w1.z, ac[6]); ac[7] = fmaf(xv, w1.w, ac[7]);
        }
        float p = 0.f;
        #pragma unroll
        for (int j = 0; j < 8; ++j)
            p += tanhf(ac[j] + ba1[n0 + j]) * Wa2[n0 + j];
        #pragma unroll
        for (int off = 1; off < 16; off <<= 1)
            p += __shfl_xor(p, off, 64);
        if (cc == 0) exv[row] = p + ba2[0];
    }
    __syncthreads();

    // ---- phase 3: sort by (exact value desc, index asc) + softmax ----------
    if (tid == 0) {
        #pragma unroll
        for (int k2 = 0; k2 < KTOP; ++k2) order[k2] = k2;
        for (int a2 = 1; a2 < KTOP; ++a2)
            for (int b2 = a2; b2 > 0; --b2) {
                int i1 = order[b2 - 1], i2 = order[b2];
                bool sw = (exv[i2] > exv[i1]) ||
                          (exv[i2] == exv[i1] && sti[i2] < sti[i1]);
                if (sw) { order[b2 - 1] = i2; order[b2] = i1; } else break;
            }
        float mx = exv[order[0]];
        float ssum = 0.f;
        for (int k2 = 0; k2 < KTOP; ++k2) {
            float e = expf(exv[order[k2]] - mx);
            attn[k2] = e; ssum += e;
        }
        float inv = 1.f / ssum;
        for (int k2 = 0; k2 < KTOP; ++k2) attn[k2] *= inv;
    }
    __syncthreads();

    if (blockIdx.x == 0 && tid < KTOP) {
        int src = order[tid];
        out[OUT_TOPI + tid] = (float)sti[src];
        out[OUT_FW + sti[src]] = attn[tid];
    }

    // ---- phase 4: embedding slice (64 dims per block) -----------------------
    if (tid < 64) {
        const int d = blockIdx.x * 64 + tid;
        float e = 0.f;
        #pragma unroll
        for (int k2 = 0; k2 < KTOP; ++k2)
            e = fmaf(attn[k2], x[(size_t)sti[order[k2]] * D_IN + d], e);
        out[OUT_EMB + d] = e;
        semb[tid] = e;
    }
    __syncthreads();

    // ---- phase 5: MLP1 partial for this 64-d slice --------------------------
    {
        float p = 0.f;
        const float* wc = Wc1 + (size_t)blockIdx.x * 64 * H_DIM + tid;
        #pragma unroll 8
        for (int j = 0; j < 64; ++j)
            p = fmaf(semb[j], wc[(size_t)j * H_DIM], p);
        hpart[blockIdx.x * H_DIM + tid] = p;
    }
}

// ---------------- Stage 3: relu + Wc2 dot + bias -----------------------------
__global__ __launch_bounds__(256) void k_logit(
    const float* __restrict__ hpart, const float* __restrict__ bc1,
    const float* __restrict__ Wc2, const float* __restrict__ bc2,
    float* __restrict__ out)
{
    __shared__ float red[256];
    const int tid = threadIdx.x;
    float h = bc1[tid];
    #pragma unroll
    for (int i = 0; i < 16; ++i) h += hpart[i * H_DIM + tid];
    h = fmaxf(h, 0.f) * Wc2[tid];
    red[tid] = h;
    __syncthreads();
    for (int off = 128; off > 0; off >>= 1) {
        if (tid < off) red[tid] += red[tid + off];
        __syncthreads();
    }
    if (tid == 0) out[OUT_LOGIT] = red[0] + bc2[0];
}

// ---------------- Launch ------------------------------------------------------
extern "C" void kernel_launch(void* const* d_in, const int* in_sizes, int n_in,
                              void* d_out, int out_size, void* d_ws, size_t ws_size,
                              hipStream_t stream)
{
    const float* x   = (const float*)d_in[0];
    const float* Wa1 = (const float*)d_in[1];
    const float* ba1 = (const float*)d_in[2];
    const float* Wa2 = (const float*)d_in[3];
    const float* ba2 = (const float*)d_in[4];
    const float* Wc1 = (const float*)d_in[5];
    const float* bc1 = (const float*)d_in[6];
    const float* Wc2 = (const float*)d_in[7];
    const float* bc2 = (const float*)d_in[8];
    float* out = (float*)d_out;
    float* ws  = (float*)d_ws;

    float* candv = ws + WS_CANDV;
    int*   candi = (int*)(ws + WS_CANDI);
    float* hpart = ws + WS_HPART;
    uint4* wpk   = (uint4*)(ws + WS_WPK);

    dim3 blk(256);
    k_prepack<<<64, blk, 0, stream>>>(Wa1, wpk, out + OUT_FW);
    k_scores<<<NBLK, blk, 0, stream>>>(x, wpk, ba1, Wa2, ba2, candv, candi);
    k_tail<<<16, blk, 0, stream>>>(candv, candi, x, Wa1, ba1, Wa2, ba2, Wc1, out, hpart);
    k_logit<<<1, blk, 0, stream>>>(hpart, bc1, Wc2, bc2, out);
}